// Round 13
// baseline (5773.391 us; speedup 1.0000x reference)
//
#include <hip/hip_runtime.h>
#include <hip/hip_bf16.h>
#include <math.h>

#define IDIM 128
#define HDIM 512
#define SDIM 64
#define BATCH 128
#define MAXT 259
#define G4 2048
#define KTOT 704    // 128 (x) + 64 (rt) + 512 (h)
#define ROUT 194    // 64 + 128 + 2
#define AFRAG_U 73728   // 8 mt * 18 ks * 64 lanes * 8 e (uints, hi|lo packed) per buffer
#define NBLK 256
#define PJ 224      // padded j-dim of part (112 uint64 slots per (row,ns))

typedef __hip_bfloat16 bf16;
typedef __attribute__((ext_vector_type(8))) short short8;
typedef __attribute__((ext_vector_type(4))) float floatx4;
typedef unsigned long long ull;

__device__ __forceinline__ float sigmoidf_(float v) { return 1.f / (1.f + expf(-v)); }
__device__ __forceinline__ float b2f(bf16 v) { return __bfloat162float(v); }
__device__ __forceinline__ float load_in(const void* p, size_t i, int isf32) {
    return isf32 ? ((const float*)p)[i] : b2f(((const bf16*)p)[i]);
}
__device__ __forceinline__ unsigned short f2bfbits(float v) {
    unsigned u = __builtin_bit_cast(unsigned, v);
    unsigned r = (u + 0x7FFFu + ((u >> 16) & 1u)) >> 16;
    return (unsigned short)r;
}
__device__ __forceinline__ float bfbits2f(unsigned short b) {
    return __builtin_bit_cast(float, (unsigned)b << 16);
}
__device__ __forceinline__ unsigned aload(const unsigned* p) {
    return __hip_atomic_load(p, __ATOMIC_RELAXED, __HIP_MEMORY_SCOPE_AGENT);
}
__device__ __forceinline__ ull aload64(const ull* p) {
    return __hip_atomic_load(p, __ATOMIC_RELAXED, __HIP_MEMORY_SCOPE_AGENT);
}
__device__ __forceinline__ void astore(unsigned* p, unsigned v) {
    __hip_atomic_store(p, v, __ATOMIC_RELAXED, __HIP_MEMORY_SCOPE_AGENT);
}
__device__ __forceinline__ void astore64(ull* p, ull v) {
    __hip_atomic_store(p, v, __ATOMIC_RELAXED, __HIP_MEMORY_SCOPE_AGENT);
}
__device__ __forceinline__ ull packf2(float a, float b) {
    return (ull)__builtin_bit_cast(unsigned, a)
         | ((ull)__builtin_bit_cast(unsigned, b) << 32);
}

// ---- root-aggregated fence-free barrier pieces ----
// arrive: drain data stores (per-wave vmcnt), then single relaxed flag store.
__device__ __forceinline__ void bar_arrive(unsigned* flags, unsigned e) {
    asm volatile("s_waitcnt vmcnt(0)" ::: "memory");
    __syncthreads();
    if (threadIdx.x == 0)
        astore(&flags[blockIdx.x * 16], e);
}
// non-root wait: one thread polls the shared gen line.
__device__ __forceinline__ void gen_wait(unsigned* gen, unsigned e) {
    if (threadIdx.x == 0)
        while (aload(gen) < e) __builtin_amdgcn_s_sleep(1);
    __syncthreads();
    __atomic_signal_fence(__ATOMIC_SEQ_CST);
}
// root: 256 threads poll the 256 flags (one each), then publish gen.
__device__ __forceinline__ void root_collect(unsigned* flags, unsigned* gen, unsigned e) {
    while (aload(&flags[threadIdx.x * 16]) < e) __builtin_amdgcn_s_sleep(2);
    __syncthreads();
    if (threadIdx.x == 0) astore(gen, e);
    __atomic_signal_fence(__ATOMIC_SEQ_CST);
}

// dtype detect (defensive): f32 data has random low halves -> bf16-exp >= 0x8F
__global__ void detect_kernel(const unsigned short* __restrict__ w, int* __restrict__ flag) {
    if (threadIdx.x == 0) {
        int isf32 = 0;
        for (int i = 0; i < 256; i++) {
            int e = (w[i] >> 7) & 0xFF;
            if (e >= 0x8F) isf32 = 1;
        }
        *flag = isf32;
    }
}

// Gate-interleaved combined weights in B-fragment layout (hi/lo bf16 split).
__global__ void prep_kernel(const void* __restrict__ Wih, const void* __restrict__ bih,
                            const void* __restrict__ Whh, const void* __restrict__ bhh,
                            unsigned short* __restrict__ WfH, unsigned short* __restrict__ WfL,
                            float* __restrict__ bc, const int* __restrict__ flag) {
    int isf32 = *flag;
    int jp = blockIdx.x;
    int u = jp >> 2, gate = jp & 3;
    int src = gate * HDIM + u;
    int jt = jp >> 4, jn = jp & 15;
    for (int k = threadIdx.x; k < KTOT; k += blockDim.x) {
        float v = (k < 192) ? load_in(Wih, (size_t)src * 192 + k, isf32)
                            : load_in(Whh, (size_t)src * HDIM + (k - 192), isf32);
        unsigned short hi = f2bfbits(v);
        unsigned short lo = f2bfbits(v - bfbits2f(hi));
        int ks = k >> 5, q = (k & 31) >> 3, e = k & 7;
        size_t d = (((size_t)jt * 22 + ks) * 64 + (q * 16 + jn)) * 8 + e;
        WfH[d] = hi;
        WfL[d] = lo;
    }
    if (threadIdx.x == 0)
        bc[jp] = load_in(bih, src, isf32) + load_in(bhh, src, isf32);
}

// Wr -> row-major bf16 hi/lo (208 rows, rows >=194 zero) + brf f32 (padded).
__global__ void wr_prep_kernel(const void* __restrict__ Wr, const void* __restrict__ br,
                               unsigned short* __restrict__ WrBh, unsigned short* __restrict__ WrBl,
                               float* __restrict__ brf, const int* __restrict__ flag) {
    int isf32 = *flag;
    int j = blockIdx.x;
    for (int k = threadIdx.x; k < HDIM; k += blockDim.x) {
        float v = (j < ROUT) ? load_in(Wr, (size_t)j * HDIM + k, isf32) : 0.f;
        unsigned short hi = f2bfbits(v);
        WrBh[(size_t)j * HDIM + k] = hi;
        WrBl[(size_t)j * HDIM + k] = f2bfbits(v - bfbits2f(hi));
    }
    if (threadIdx.x == 0) brf[j] = (j < ROUT) ? load_in(br, j, isf32) : 0.f;
}

// ---------------- persistent kernel (R12 + root barrier + hidden h-staging) ----------------
__global__ __launch_bounds__(256) void persist_kernel(
        const void* __restrict__ x,
        const unsigned short* __restrict__ WfH, const unsigned short* __restrict__ WfL,
        const float* __restrict__ bc,
        const unsigned short* __restrict__ WrBh, const unsigned short* __restrict__ WrBl,
        const float* __restrict__ brf,
        unsigned* __restrict__ AfP,          // 2 x AFRAG_U uints (hi | lo<<16)
        float* __restrict__ part,            // [128 rows][32 ns][PJ j] f32
        unsigned short* __restrict__ Vg,     // [128][259][64] bf16, block-private
        void* __restrict__ dout, const int* __restrict__ flag,
        unsigned* __restrict__ flags, unsigned* __restrict__ gen) {
    __shared__ __align__(16) short Ahs[18 * 64 * 8];          // staged A hi; pt overlay
    __shared__ __align__(16) short Als[18 * 64 * 8];          // staged A lo
    __shared__ __align__(16) unsigned short wrsl[208 * 16];   // Wr hi slice (16 cols of ns)
    __shared__ __align__(16) unsigned short wrslL[208 * 16];  // Wr lo slice
    __shared__ __align__(16) float scr[4][16][20];            // epilogue tile; redP overlay
    __shared__ __align__(16) float hl[16][17];
    __shared__ __align__(16) float outs[208];
    __shared__ __align__(16) float sL[324];
    __shared__ __align__(16) float aL[324];
    __shared__ __align__(16) float red[4][64];
    __shared__ __align__(16) float brS[208];
    __shared__ __align__(16) float bcS[64];

    const int tid = threadIdx.x, lane = tid & 63, wv = tid >> 6;
    const int blk = blockIdx.x, ms = blk >> 5, ns = blk & 31;
    const int isf32 = *flag;
    const int is_row = (blk < 128), is_root = (blk == NBLK - 1);
    float* const pt = (float*)Ahs;       // 16 x 212 f32 overlay

    for (int i = tid; i < 208 * 16; i += 256) {
        int j = i >> 4, ui = i & 15;
        wrsl[i]  = WrBh[(size_t)j * HDIM + ns * 16 + ui];
        wrslL[i] = WrBl[(size_t)j * HDIM + ns * 16 + ui];
    }
    for (int i = tid; i < 208; i += 256) brS[i] = brf[i];
    if (tid < 64) bcS[tid] = bc[ns * 64 + tid];
    for (int i = tid; i < 324; i += 256) { sL[i] = 0.f; aL[i] = 0.f; }
    // initial A-frags are all zero (rt=h=0 at t=0)
    for (int i = tid; i < 18 * 64 * 8; i += 256) { Ahs[i] = 0; Als[i] = 0; }
    float cc = 0.f;
    __syncthreads();

    const short8* WH = (const short8*)WfH;
    const short8* WL = (const short8*)WfL;
    const int nt = ns * 4 + wv;
    unsigned short* Vrow = Vg + (size_t)blk * MAXT * SDIM;    // blocks 0..127 only

    for (int t = 0; t < MAXT; t++) {
        const int cur = t & 1, nxt = cur ^ 1;
        const ull* AfPc64 = (const ull*)(AfP + (size_t)cur * AFRAG_U);
        ull* AfPn64 = (ull*)(AfP + (size_t)nxt * AFRAG_U);
        const int use_x = (t < 129);

        // ---- P0: stage ONLY rt frags (ks 0,1) — h was pre-staged last step ----
        if (t > 0) {
            #pragma unroll
            for (int i = 0; i < 2; i++) {
                int idx = tid + i * 256;        // 0..511
                int ksi = idx >> 8, rem = idx & 255, l = rem >> 2, j = rem & 3;
                ull q = aload64(AfPc64 + ((size_t)(ms * 18 + ksi) * 64 + l) * 4 + j);
                int si = (ksi * 64 + l) * 8 + j * 2;
                unsigned hw = (unsigned)(q & 0xffffu) | ((unsigned)((q >> 32) & 0xffffu) << 16);
                unsigned lw = (unsigned)((q >> 16) & 0xffffu) | ((unsigned)(q >> 48) << 16);
                ((unsigned*)Ahs)[si >> 1] = hw;
                ((unsigned*)Als)[si >> 1] = lw;
            }
            __syncthreads();
        }

        // ---- P1: gates MFMA (one 16x16 acc per wave) ----
        floatx4 acc = {0.f, 0.f, 0.f, 0.f};
        const short8* wb  = WH + (size_t)nt * 22 * 64;
        const short8* wbl = WL + (size_t)nt * 22 * 64;
        if (use_x) {
            int m = lane & 15, q = lane >> 4;
            size_t xrow = ((size_t)t * BATCH + ms * 16 + m) * IDIM + q * 8;
            #pragma unroll
            for (int ks = 0; ks < 4; ks++) {
                short8 a;
                if (isf32) {
                    const float* xf = (const float*)x + xrow + ks * 32;
                    #pragma unroll
                    for (int i = 0; i < 8; i++) a[i] = (short)f2bfbits(xf[i]);
                } else {
                    a = *(const short8*)((const unsigned short*)x + xrow + ks * 32);
                }
                acc = __builtin_amdgcn_mfma_f32_16x16x32_bf16(a, wb[ks * 64 + lane], acc, 0, 0, 0);
                if (isf32)
                    acc = __builtin_amdgcn_mfma_f32_16x16x32_bf16(a, wbl[ks * 64 + lane], acc, 0, 0, 0);
            }
        }
        #pragma unroll 6
        for (int ksi = 0; ksi < 18; ksi++) {
            int ks = 4 + ksi;
            short8 ah  = *(const short8*)&Ahs[(ksi * 64 + lane) * 8];
            short8 al8 = *(const short8*)&Als[(ksi * 64 + lane) * 8];
            short8 bh = wb[ks * 64 + lane];
            acc = __builtin_amdgcn_mfma_f32_16x16x32_bf16(ah, bh, acc, 0, 0, 0);
            acc = __builtin_amdgcn_mfma_f32_16x16x32_bf16(al8, bh, acc, 0, 0, 0);
            if (isf32)
                acc = __builtin_amdgcn_mfma_f32_16x16x32_bf16(ah, wbl[ks * 64 + lane], acc, 0, 0, 0);
        }
        {
            int n = lane & 15, m0 = (lane >> 4) * 4;
            #pragma unroll
            for (int r = 0; r < 4; r++) scr[wv][m0 + r][n] = acc[r];
        }
        __syncthreads();
        // cell epilogue
        {
            int r = tid >> 4, ul = tid & 15;
            float4 g = *(const float4*)&scr[ul >> 2][r][(ul & 3) * 4];
            float4 bb = *(const float4*)&bcS[ul * 4];
            float c2 = sigmoidf_(g.y + bb.y) * cc + sigmoidf_(g.x + bb.x) * tanhf(g.z + bb.z);
            float h2 = sigmoidf_(g.w + bb.w) * tanhf(c2);
            cc = c2;
            hl[r][ul] = h2;
        }
        __syncthreads();   // hl ready; Ahs dead -> pt overlay OK
        // publish h tile as packed uint64 frag stores
        if (tid < 128) {
            int r = tid >> 3, ulp = (tid & 7) * 2;
            float h0 = hl[r][ulp], h1 = hl[r][ulp + 1];
            unsigned short hb0 = f2bfbits(h0);
            unsigned short lb0 = f2bfbits(h0 - bfbits2f(hb0));
            unsigned short hb1 = f2bfbits(h1);
            unsigned short lb1 = f2bfbits(h1 - bfbits2f(hb1));
            unsigned u0 = (unsigned)hb0 | ((unsigned)lb0 << 16);
            unsigned u1 = (unsigned)hb1 | ((unsigned)lb1 << 16);
            int u_g = ns * 16 + ulp;
            int ksi2 = 2 + (u_g >> 5), q = (u_g & 31) >> 3, e = u_g & 7;
            size_t fi = (((size_t)ms * 18 + ksi2) * 64 + q * 16 + r) * 8 + e;
            astore64(AfPn64 + fi / 2, (ull)u0 | ((ull)u1 << 32));
        }
        // readout partials -> LDS tile pt[16][212]
        {
            int jset = tid >> 4, r2 = tid & 15;
            float* prow = pt + r2 * 212;
            #pragma unroll
            for (int i = 0; i < 13; i++) {
                int j = jset * 13 + i;
                float p = 0.f;
                #pragma unroll
                for (int k = 0; k < 16; k++) p += bfbits2f(wrsl[j * 16 + k]) * hl[r2][k];
                if (isf32) {
                    #pragma unroll
                    for (int k = 0; k < 16; k++) p += bfbits2f(wrslL[j * 16 + k]) * hl[r2][k];
                }
                prow[j] = p;
            }
        }
        __syncthreads();
        // coalesced publish of partials
        {
            #pragma unroll
            for (int it = 0; it < 4; it++) {
                int rloc = wv * 4 + it;
                int row = ms * 16 + rloc;
                const float* pr = pt + rloc * 212;
                ull* pb64 = (ull*)(part + (((size_t)row * 32) + ns) * PJ);
                astore64(pb64 + lane, packf2(pr[2 * lane], pr[2 * lane + 1]));
                if (lane < 40)
                    astore64(pb64 + 64 + lane, packf2(pr[128 + 2 * lane], pr[129 + 2 * lane]));
            }
        }

        // ---- barrier 1 arrivals ----
        const unsigned e1 = 2 * t + 1, e2 = 2 * t + 2;
        if (is_row) bar_arrive(flags, e1);
        else        bar_arrive(flags, e2);   // gates-only: single arrival per step
        if (is_root) root_collect(flags, gen, e1);

        if (is_row) {
            gen_wait(gen, e1);
            // ---- P2 ----
            const int brow = blk;
            const int msb = brow >> 4, mloc = brow & 15;
            float* redP = (float*)scr;   // overlay (scr dead in P2)
            if (tid < 208) {
                int half = (tid >= 104) ? 1 : 0;
                int pr = tid - half * 104;              // 0..103, j-pair index
                const ull* pb64 = (const ull*)part;
                size_t basep = ((size_t)brow * 32 + half * 16) * (PJ / 2) + pr;
                float s0 = 0.f, s1 = 0.f;
                #pragma unroll 4
                for (int nsI = 0; nsI < 16; nsI++) {
                    ull q = aload64(pb64 + basep + (size_t)nsI * (PJ / 2));
                    s0 += __builtin_bit_cast(float, (unsigned)q);
                    s1 += __builtin_bit_cast(float, (unsigned)(q >> 32));
                }
                redP[(half * 104 + pr) * 2 + 0] = s0;
                redP[(half * 104 + pr) * 2 + 1] = s1;
            }
            __syncthreads();
            if (tid < 208) {
                int pr = tid >> 1, e = tid & 1;
                outs[tid] = redP[pr * 2 + e] + redP[(104 + pr) * 2 + e] + brS[tid];
            }
            __syncthreads();
            if (wv == 0) {
                float uval = sigmoidf_(outs[192]);
                float dval = sigmoidf_(outs[193]);
                Vrow[t * SDIM + lane] = f2bfbits(outs[lane]);
                int ebase = lane * 5;
                float sv[5], suf[5];
                #pragma unroll
                for (int j = 0; j < 5; j++) {
                    int e = ebase + j;
                    sv[j] = (e < MAXT) ? sL[e] : 0.f;
                }
                suf[4] = sv[4];
                #pragma unroll
                for (int j = 3; j >= 0; j--) suf[j] = sv[j] + suf[j + 1];
                float ltot = suf[0];
                float accs = ltot;
                #pragma unroll
                for (int off = 1; off < 64; off <<= 1) {
                    float y = __shfl_down(accs, off, 64);
                    if (lane + off < 64) accs += y;
                }
                float after_lane = accs - ltot;
                #pragma unroll
                for (int j = 0; j < 5; j++) {
                    int e = ebase + j;
                    if (e < MAXT) {
                        float prod = after_lane + (suf[j] - sv[j]);
                        float sp = (e == t) ? dval
                                            : fmaxf(0.f, sv[j] - fmaxf(0.f, uval - prod));
                        float inner = fmaxf(0.f, 1.f - prod - sp);
                        sL[e] = sp;
                        aL[e] = fminf(sp, inner);
                    }
                }
            }
            __syncthreads();
            {
                float racc = 0.f;
                for (int i2 = wv; i2 <= t; i2 += 4)
                    racc += aL[i2] * bfbits2f(Vrow[i2 * SDIM + lane]);
                red[wv][lane] = racc;
            }
            __syncthreads();
            if (wv == 0) {
                float rtv = red[0][lane] + red[1][lane] + red[2][lane] + red[3][lane];
                float rtn = __shfl_down(rtv, 1, 64);
                if ((lane & 1) == 0) {
                    unsigned short hb0 = f2bfbits(rtv);
                    unsigned short lb0 = f2bfbits(rtv - bfbits2f(hb0));
                    unsigned short hb1 = f2bfbits(rtn);
                    unsigned short lb1 = f2bfbits(rtn - bfbits2f(hb1));
                    unsigned u0 = (unsigned)hb0 | ((unsigned)lb0 << 16);
                    unsigned u1 = (unsigned)hb1 | ((unsigned)lb1 << 16);
                    int d0 = lane;
                    int ksi = d0 >> 5, q = (d0 & 31) >> 3, e = d0 & 7;
                    size_t fi = (((size_t)msb * 18 + ksi) * 64 + q * 16 + mloc) * 8 + e;
                    astore64(AfPn64 + fi / 2, (ull)u0 | ((ull)u1 << 32));
                }
            } else if (wv == 1 && t >= 129) {
                float a = outs[64 + lane];
                float bvv = outs[128 + lane];
                float m = fmaxf(a, bvv);
                #pragma unroll
                for (int off = 32; off; off >>= 1) m = fmaxf(m, __shfl_xor(m, off, 64));
                float e = expf(a - m) + expf(bvv - m);
                #pragma unroll
                for (int off = 32; off; off >>= 1) e += __shfl_xor(e, off, 64);
                float ls = logf(e) + m;
                size_t base = ((size_t)(t - 129) * BATCH + blk) * IDIM;
                if (isf32) {
                    ((float*)dout)[base + lane] = a - ls;
                    ((float*)dout)[base + lane + 64] = bvv - ls;
                } else {
                    ((bf16*)dout)[base + lane] = __float2bfloat16(a - ls);
                    ((bf16*)dout)[base + lane + 64] = __float2bfloat16(bvv - ls);
                }
            }
            bar_arrive(flags, e2);
        } else if (!is_root) {
            gen_wait(gen, e1);   // h-frags of this ms-group all published now
        }

        // ---- hidden h-staging (ks 2..17) for step t+1, from AfPn (final at b1) ----
        {
            #pragma unroll
            for (int i = 0; i < 16; i++) {
                int idx = tid + i * 256;        // 0..4095
                int ksi = 2 + (idx >> 8), rem = idx & 255, l = rem >> 2, j = rem & 3;
                ull q = aload64(AfPn64 + ((size_t)(ms * 18 + ksi) * 64 + l) * 4 + j);
                int si = (ksi * 64 + l) * 8 + j * 2;
                unsigned hw = (unsigned)(q & 0xffffu) | ((unsigned)((q >> 32) & 0xffffu) << 16);
                unsigned lw = (unsigned)((q >> 16) & 0xffffu) | ((unsigned)(q >> 48) << 16);
                ((unsigned*)Ahs)[si >> 1] = hw;
                ((unsigned*)Als)[si >> 1] = lw;
            }
        }

        // ---- barrier 2 ----
        if (is_root) root_collect(flags, gen, e2);
        else         gen_wait(gen, e2);
    }
}

extern "C" void kernel_launch(void* const* d_in, const int* in_sizes, int n_in,
                              void* d_out, int out_size, void* d_ws, size_t ws_size,
                              hipStream_t stream) {
    const void* x   = d_in[0];
    const void* Wih = d_in[1];
    const void* bih = d_in[2];
    const void* Whh = d_in[3];
    const void* bhh = d_in[4];
    const void* Wr  = d_in[5];
    const void* br  = d_in[6];

    char* base = (char*)d_ws;
    size_t off = 0;
    int* flag = (int*)base;                                   off += 64;
    unsigned* flags = (unsigned*)(base + off);                off += 256 * 64;
    unsigned* gen = (unsigned*)(base + off);                  off += 64;
    unsigned short* WfH  = (unsigned short*)(base + off);     off += (size_t)G4 * KTOT * 2;
    unsigned short* WfL  = (unsigned short*)(base + off);     off += (size_t)G4 * KTOT * 2;
    unsigned short* WrBh = (unsigned short*)(base + off);     off += (size_t)208 * HDIM * 2;
    unsigned short* WrBl = (unsigned short*)(base + off);     off += (size_t)208 * HDIM * 2;
    float* bc   = (float*)(base + off);                       off += G4 * 4;
    float* brf  = (float*)(base + off);                       off += 1024;
    unsigned* AfP = (unsigned*)(base + off);                  size_t af_off = off;
                                                              off += (size_t)2 * AFRAG_U * 4;
    float* part = (float*)(base + off);                       off += (size_t)BATCH * 32 * PJ * 4;
    unsigned short* Vg = (unsigned short*)(base + off);       off += (size_t)BATCH * MAXT * SDIM * 2;
    // total ~15 MB

    hipMemsetAsync(base + 64, 0, 256 * 64 + 64, stream);               // flags + gen
    hipMemsetAsync(base + af_off, 0, (size_t)2 * AFRAG_U * 4, stream); // A-frag buffers

    detect_kernel<<<1, 64, 0, stream>>>((const unsigned short*)Wih, flag);
    prep_kernel<<<G4, 256, 0, stream>>>(Wih, bih, Whh, bhh, WfH, WfL, bc, flag);
    wr_prep_kernel<<<208, 256, 0, stream>>>(Wr, br, WrBh, WrBl, brf, flag);

    persist_kernel<<<NBLK, 256, 0, stream>>>(x, WfH, WfL, bc, WrBh, WrBl, brf,
                                             AfP, part, Vg, d_out, flag, flags, gen);

    (void)in_sizes; (void)n_in; (void)out_size; (void)ws_size;
}